// Round 16
// baseline (441.215 us; speedup 1.0000x reference)
//
#include <hip/hip_runtime.h>
#include <math.h>

#define NN 30000
#define EE 480000
#define FIN 100
#define NCLS 47
#define SCAN_B 118  // ceil(30000/256)

typedef unsigned short ushortt;
typedef __attribute__((ext_vector_type(8))) short bf16x8;
typedef __attribute__((ext_vector_type(4))) float f32x4;
typedef __attribute__((ext_vector_type(2))) float f32x2;

// ---------------- static device workspace ----------------
// Xb/Fb/Wc* use a bank-conflict-killing swizzle: within each 64-col K-window,
// 8-ushort chunk index is XORed with (row & 7) (r15: conflicts 5.85M -> 682k).
// g_als/g_ald are HEAD-MAJOR [4][NN]: the gemm epilogue writes 32B contiguous
// runs per head (kills ~15 MB of 4B-scatter sector write amplification, r15 WRITE).
__device__ unsigned char g_H8[(size_t)NN * 256];  // fp8 e4m3 h for the gathers (l2: ld=192)
__device__ ushortt g_Sb[(size_t)NN * 256];   // skip/pre-BN accumulator, bf16 (layers 0/1)
__device__ float   g_S2[(size_t)NN * 48];    // layer-2 skip, fp32 [N,47]
__device__ ushortt g_Fb[(size_t)NN * 256];   // post-BN features bf16, SWIZZLED
__device__ ushortt g_Xb[(size_t)NN * 128];   // x padded 100->128, bf16, SWIZZLED
__device__ ushortt g_Wc0[512 * 128];         // [W0 | SW0]^T bf16, SWIZZLED
__device__ ushortt g_Wc1[512 * 256];         // [W1 | SW1]^T, SWIZZLED
__device__ ushortt g_Wc2[235 * 256];         // [W2(188) | SW2(47)]^T, SWIZZLED
__device__ float g_als[4 * NN];              // head-major
__device__ float g_ald[4 * NN];              // head-major
__device__ int   g_rowptr[NN + 1];
__device__ int   g_counts[NN];
__device__ int   g_bsum[128];                // per-block sums for scan
__device__ int   g_esrc[EE];                 // src node in CSR (dst-sorted) order
__device__ float g_stat[1024];               // [0:512) layer0, [512:1024) layer1 sum/sumsq

// ---------------- helpers ----------------
__device__ __forceinline__ float wsum(float v) {
#pragma unroll
  for (int o = 32; o > 0; o >>= 1) v += __shfl_xor(v, o, 64);
  return v;
}
__device__ __forceinline__ float lrelu(float x) { return x > 0.f ? x : 0.2f * x; }
__device__ __forceinline__ ushortt f2bf(float f) {
  unsigned int u = __float_as_uint(f);
  unsigned int r = u + 0x7FFF + ((u >> 16) & 1);
  return (ushortt)(r >> 16);
}
__device__ __forceinline__ float bf2f(ushortt u) {
  return __uint_as_float(((unsigned int)u) << 16);
}
__device__ __forceinline__ unsigned int pk4_fp8(float f0, float f1, float f2, float f3) {
  unsigned int r = 0;
  r = __builtin_amdgcn_cvt_pk_fp8_f32(f0, f1, r, false);
  r = __builtin_amdgcn_cvt_pk_fp8_f32(f2, f3, r, true);
  return r;
}
// swizzled column index: window=64 cols, chunk=8 cols, chunk ^= (row&7)
__device__ __forceinline__ int swz(int row, int k) {
  return (k & ~63) | ((((k >> 3) & 7) ^ (row & 7)) << 3) | (k & 7);
}
// async global->LDS, 16B per lane; lds dest = base + lane*16 (wave-uniform base)
__device__ __forceinline__ void glds16(const ushortt* gp, ushortt* lp) {
  __builtin_amdgcn_global_load_lds(
      (const __attribute__((address_space(1))) unsigned int*)gp,
      (__attribute__((address_space(3))) unsigned int*)lp, 16, 0, 0);
}

// ---------------- CSR build ----------------
__global__ void count_kernel(const int* __restrict__ dst) {
  int e = blockIdx.x * blockDim.x + threadIdx.x;
  if (e < EE) atomicAdd(&g_counts[dst[e]], 1);
}
__global__ void scan1_kernel() {
  int i = blockIdx.x * 256 + threadIdx.x;
  int v = (i < NN) ? g_counts[i] : 0;
  __shared__ int sh[4];
  float fv = (float)v;
  fv = wsum(fv);
  if ((threadIdx.x & 63) == 0) sh[threadIdx.x >> 6] = (int)fv;
  __syncthreads();
  if (threadIdx.x == 0) g_bsum[blockIdx.x] = sh[0] + sh[1] + sh[2] + sh[3];
}
__global__ void scan2_kernel() {
  __shared__ int sh[128];
  int t = threadIdx.x;
  int v = (t < SCAN_B) ? g_bsum[t] : 0;
  sh[t] = v;
  __syncthreads();
  for (int off = 1; off < 128; off <<= 1) {
    int x = (t >= off) ? sh[t - off] : 0;
    __syncthreads();
    sh[t] += x;
    __syncthreads();
  }
  g_bsum[t] = sh[t] - v;  // exclusive
}
__global__ void scan3_kernel() {
  __shared__ int sh[256];
  int t = threadIdx.x;
  int i = blockIdx.x * 256 + t;
  int v = (i < NN) ? g_counts[i] : 0;
  sh[t] = v;
  __syncthreads();
  for (int off = 1; off < 256; off <<= 1) {
    int x = (t >= off) ? sh[t - off] : 0;
    __syncthreads();
    sh[t] += x;
    __syncthreads();
  }
  if (i < NN) {
    g_rowptr[i] = g_bsum[blockIdx.x] + sh[t] - v;
    g_counts[i] = 0;
  }
  if (i == NN - 1) g_rowptr[NN] = EE;
}
__global__ void scatter_kernel(const int* __restrict__ dst, const int* __restrict__ src) {
  int e = blockIdx.x * blockDim.x + threadIdx.x;
  if (e < EE) {
    int d = dst[e];
    int pos = g_rowptr[d] + atomicAdd(&g_counts[d], 1);
    g_esrc[pos] = src[e];
  }
}

// ---------------- conversions + all zero-init (runs FIRST, replaces memsets) ----------
#define CW0 (512 * 128)
#define CW1 (512 * 256)
#define CW2 (235 * 256)
__global__ void conv_kernel(const float* __restrict__ w0, const float* __restrict__ sw0,
                            const float* __restrict__ w1, const float* __restrict__ sw1,
                            const float* __restrict__ w2, const float* __restrict__ sw2,
                            const float* __restrict__ x) {
  int i = blockIdx.x * blockDim.x + threadIdx.x;
  if (i < CW0) {
    int m = i >> 7, k = i & 127;
    float v = 0.f;
    if (k < FIN) v = (m < 256) ? w0[k * 256 + m] : sw0[k * 256 + (m - 256)];
    g_Wc0[(m << 7) | swz(m, k)] = f2bf(v);
    return;
  }
  i -= CW0;
  if (i < CW1) {
    int m = i >> 8, k = i & 255;
    float v = (m < 256) ? w1[k * 256 + m] : sw1[k * 256 + (m - 256)];
    g_Wc1[(m << 8) | swz(m, k)] = f2bf(v);
    return;
  }
  i -= CW1;
  if (i < CW2) {
    int m = i >> 8, k = i & 255;
    float v = (m < 188) ? w2[(size_t)k * 188 + m] : sw2[(size_t)k * 47 + (m - 188)];
    g_Wc2[(m << 8) | swz(m, k)] = f2bf(v);
    return;
  }
  i -= CW2;
  if (i < NN * 128) {
    int r = i >> 7, k = i & 127;
    g_Xb[(r << 7) | swz(r, k)] = (k < FIN) ? f2bf(x[r * FIN + k]) : 0;
    return;
  }
  i -= NN * 128;
  if (i < NN) {
    g_counts[i] = 0;
    return;
  }
  i -= NN;
  if (i < 1024) g_stat[i] = 0.f;
}

// ---------------- MFMA GEMM, 64x128 tile, BK=64, global_load_lds, swizzled LDS ----------
// A bf16 [nrows,Kp] SWIZZLED; Wt bf16 [M][Kp] SWIZZLED; cols < S -> out8 fp8 (pad47
// remaps c -> (c/47)*48 + c%47, ld8=192); cols >= S -> skip bf16 (out2b) or fp32
// (out2f), +bias2. Attention logits fused, head-major coalesced writes (layers 0/1)
// or atomics (layer 2). Epilogue FULLY UNROLLED (round-7 scratch-spill lesson).
__global__ __launch_bounds__(256) void mfma_gemm(
    const ushortt* __restrict__ A, const ushortt* __restrict__ Wt,
    unsigned char* __restrict__ out8, ushortt* __restrict__ out2b,
    float* __restrict__ out2f,
    int nrows, int Kp, int M, int S, int ld8, int ld2,
    const float* __restrict__ bias2, int pad47,
    const float* __restrict__ a_s, const float* __restrict__ a_d,
    float* __restrict__ alsp, float* __restrict__ aldp) {
  __shared__ __align__(16) ushortt smem[(64 + 128) * 64];  // As(64x64) | Ws(128x64), 24 KB
  ushortt* As = smem;
  ushortt* Ws = smem + 64 * 64;
  float* Ls = (float*)smem;  // epilogue reuse: 32 x (stride 132) f32 = 16.9 KB
  int t = threadIdx.x;
  int wave = t >> 6, lane = t & 63;
  int row0 = blockIdx.y * 64, col0 = blockIdx.x * 128;
  int wr = wave >> 1, wc = wave & 1;  // 2 row-halves x 2 col-halves
  int m16 = lane & 15, q = lane >> 4;
  int rin8 = lane >> 3;            // 0..7 row within 8-row staging group
  int koff = (lane & 7) * 8;       // k offset in ushorts within 64-k row

  f32x4 acc[2][4];
#pragma unroll
  for (int i = 0; i < 2; i++)
#pragma unroll
    for (int j = 0; j < 4; j++) acc[i][j] = (f32x4){0.f, 0.f, 0.f, 0.f};

  for (int k0 = 0; k0 < Kp; k0 += 64) {
#pragma unroll
    for (int r = 0; r < 2; r++) {
      int lrow = wave * 16 + r * 8;
      int ga = min(row0 + lrow + rin8, nrows - 1);
      glds16(A + (size_t)ga * Kp + k0 + koff, &As[lrow * 64]);
    }
#pragma unroll
    for (int r = 0; r < 4; r++) {
      int lrow = wave * 32 + r * 8;
      int gw = min(col0 + lrow + rin8, M - 1);
      glds16(Wt + (size_t)gw * Kp + k0 + koff, &Ws[lrow * 64]);
    }
    __syncthreads();
#pragma unroll
    for (int c = 0; c < 2; c++) {
      bf16x8 af[2], bf[4];
#pragma unroll
      for (int i = 0; i < 2; i++) {
        int row = wr * 32 + i * 16 + m16;
        int ch = (c * 4 + q) ^ (row & 7);  // de-swizzle: conflict-free across m16 rows
        af[i] = *(const bf16x8*)(&As[row * 64 + ch * 8]);
      }
#pragma unroll
      for (int i = 0; i < 4; i++) {
        int row = wc * 64 + i * 16 + m16;
        int ch = (c * 4 + q) ^ (row & 7);
        bf[i] = *(const bf16x8*)(&Ws[row * 64 + ch * 8]);
      }
#pragma unroll
      for (int rt = 0; rt < 2; rt++)
#pragma unroll
        for (int ct = 0; ct < 4; ct++)
          acc[rt][ct] = __builtin_amdgcn_mfma_f32_16x16x32_bf16(af[rt], bf[ct], acc[rt][ct], 0, 0, 0);
    }
    __syncthreads();
  }

  // ---- coalesced epilogue via LDS bounce: 2 chunks of 32 rows x 128 cols ----
  bool all1 = (!pad47) && (col0 + 128 <= S);
  bool all2 = (col0 >= S);
  int row8 = t >> 3, seg = t & 7;
#pragma unroll
  for (int it = 0; it < 2; it++) {
    if (wr == it) {
#pragma unroll
      for (int rt = 0; rt < 2; rt++) {
#pragma unroll
        for (int ctt = 0; ctt < 4; ctt++) {
#pragma unroll
          for (int reg = 0; reg < 4; reg++) {
            int rloc = rt * 16 + q * 4 + reg;  // 0..31
            Ls[rloc * 132 + wc * 64 + ctt * 16 + m16] = acc[rt][ctt][reg];
          }
        }
      }
    }
    __syncthreads();
    int grow = row0 + it * 32 + row8;
    if (grow < nrows) {
      const float* lrow = Ls + row8 * 132 + seg * 16;
      int cbase = col0 + seg * 16;
      if (all1) {
        unsigned int q8[4];
#pragma unroll
        for (int kk = 0; kk < 4; kk++)
          q8[kk] = pk4_fp8(lrow[kk * 4], lrow[kk * 4 + 1], lrow[kk * 4 + 2], lrow[kk * 4 + 3]);
        uint4 v8 = {q8[0], q8[1], q8[2], q8[3]};
        *(uint4*)(out8 + (size_t)grow * ld8 + cbase) = v8;
        // fused attention-logit partials: this thread covers 16 ch of head cbase>>6
        float s_p = 0.f, d_p = 0.f;
#pragma unroll
        for (int kk = 0; kk < 16; kk++) {
          s_p += lrow[kk] * a_s[cbase + kk];
          d_p += lrow[kk] * a_d[cbase + kk];
        }
        s_p += __shfl_xor(s_p, 1, 64); s_p += __shfl_xor(s_p, 2, 64);
        d_p += __shfl_xor(d_p, 1, 64); d_p += __shfl_xor(d_p, 2, 64);
        if ((seg & 3) == 0) {
          int head = cbase >> 6;
          alsp[head * NN + grow] = s_p;   // head-major: 32B-contiguous per chunk
          aldp[head * NN + grow] = d_p;
        }
      } else if (all2) {
        const float* brow = bias2 + (cbase - S);
        // bf16 skip store (layers 0/1): 16 cols -> 8 packed uints -> 2 uint4 stores
        ushortt* orow = out2b + (size_t)grow * ld2 + (cbase - S);
        unsigned int pk[8];
#pragma unroll
        for (int kk = 0; kk < 8; kk++) {
          unsigned int lo = f2bf(lrow[kk * 2] + brow[kk * 2]);
          unsigned int hi = f2bf(lrow[kk * 2 + 1] + brow[kk * 2 + 1]);
          pk[kk] = lo | (hi << 16);
        }
        uint4 v0 = {pk[0], pk[1], pk[2], pk[3]};
        uint4 v1 = {pk[4], pk[5], pk[6], pk[7]};
        *(uint4*)(orow) = v0;
        *(uint4*)(orow + 8) = v1;
      } else {
        // layer-2 mixed tile: scalar h stores (fp8, padded 47->48) + fp32 skip cols +
        // atomic logit partials (head = c/47, at most 2 heads per thread)
        float pa0 = 0.f, pa1 = 0.f, pd0 = 0.f, pd1 = 0.f;
        int h0 = cbase / 47;
        for (int kk = 0; kk < 16; kk++) {
          int c = cbase + kk;
          if (c >= M) break;
          float v = lrow[kk];
          if (c < S) {
            int hd = c / 47, ch = c - hd * 47;
            int c1 = hd * 48 + ch;
            out8[(size_t)grow * ld8 + c1] =
                (unsigned char)(pk4_fp8(v, 0.f, 0.f, 0.f) & 0xFF);
            if (ch == 46) out8[(size_t)grow * ld8 + c1 + 1] = 0;
            float sw = a_s[hd * 47 + ch], dw = a_d[hd * 47 + ch];
            if (hd == h0) { pa0 += v * sw; pd0 += v * dw; }
            else { pa1 += v * sw; pd1 += v * dw; }
          } else {
            out2f[(size_t)grow * ld2 + (c - S)] = v + bias2[c - S];
          }
        }
        if (pad47 && cbase < S) {
          if (pa0 != 0.f || pd0 != 0.f) {
            atomicAdd(&alsp[h0 * NN + grow], pa0);
            atomicAdd(&aldp[h0 * NN + grow], pd0);
          }
          if ((pa1 != 0.f || pd1 != 0.f) && h0 + 1 < 4) {
            atomicAdd(&alsp[(h0 + 1) * NN + grow], pa1);
            atomicAdd(&aldp[(h0 + 1) * NN + grow], pd1);
          }
        }
      }
    }
    __syncthreads();
  }
}

// ---------------- fused softmax + aggregate + skip-add, C=64 concat (fp8 gather) --------
// Skip buffer Sb is bf16 (RMW). Logits are head-major. No max-subtraction: logits are
// lrelu of O(1) sums; exp cannot overflow and softmax is shift-invariant.
__global__ __launch_bounds__(64) void attn_kernel(const unsigned char* __restrict__ H8,
                                                  const float* __restrict__ bias,
                                                  ushortt* __restrict__ Sb) {
  __shared__ __align__(16) float p_sh[64 * 4];
  __shared__ int s_sh[64];
  int n = blockIdx.x, lane = threadIdx.x;
  int rs = g_rowptr[n], deg = g_rowptr[n + 1] - rs;
  float ald0 = g_ald[0 * NN + n], ald1 = g_ald[1 * NN + n];
  float ald2 = g_ald[2 * NN + n], ald3 = g_ald[3 * NN + n];
  int q = lane >> 4;
  float den0 = 0, den1 = 0, den2 = 0, den3 = 0;
  float a0 = 0, a1 = 0, a2 = 0, a3 = 0;
  for (int base = 0; base < deg; base += 64) {
    int j = base + lane;
    float p0 = 0, p1 = 0, p2 = 0, p3 = 0;
    int s = 0;
    if (j < deg) {
      s = g_esrc[rs + j];
      p0 = __expf(lrelu(g_als[0 * NN + s] + ald0)); den0 += p0;
      p1 = __expf(lrelu(g_als[1 * NN + s] + ald1)); den1 += p1;
      p2 = __expf(lrelu(g_als[2 * NN + s] + ald2)); den2 += p2;
      p3 = __expf(lrelu(g_als[3 * NN + s] + ald3)); den3 += p3;
    }
    p_sh[lane * 4 + 0] = p0; p_sh[lane * 4 + 1] = p1;
    p_sh[lane * 4 + 2] = p2; p_sh[lane * 4 + 3] = p3;
    s_sh[lane] = s;
    __syncthreads();
    int cnt = min(64, deg - base);
    for (int jj = 0; jj < cnt; jj++) {
      int ss = s_sh[jj];
      float p = p_sh[jj * 4 + q];
      unsigned int hv = *(const unsigned int*)(H8 + (size_t)ss * 256 + 4 * lane);
      f32x2 lo = __builtin_amdgcn_cvt_pk_f32_fp8(hv, false);
      f32x2 hi = __builtin_amdgcn_cvt_pk_f32_fp8(hv, true);
      a0 += p * lo.x;
      a1 += p * lo.y;
      a2 += p * hi.x;
      a3 += p * hi.y;
    }
    __syncthreads();
  }
  den0 = wsum(den0); den1 = wsum(den1); den2 = wsum(den2); den3 = wsum(den3);
  float denq = (q == 0) ? den0 : (q == 1) ? den1 : (q == 2) ? den2 : den3;
  float inv = 1.f / (denq + 1e-16f);
  size_t o = (size_t)n * 256 + 4 * lane;
  ushort4 sv = *(const ushort4*)(Sb + o);
  float4 bv = *(const float4*)(bias + 4 * lane);
  ushort4 ov;
  ov.x = f2bf(a0 * inv + bv.x + bf2f(sv.x));
  ov.y = f2bf(a1 * inv + bv.y + bf2f(sv.y));
  ov.z = f2bf(a2 * inv + bv.z + bf2f(sv.z));
  ov.w = f2bf(a3 * inv + bv.w + bf2f(sv.w));
  *(ushort4*)(Sb + o) = ov;
}

// ---------------- layer-2: softmax + aggregate (fp8, ld=192) + mean + skip + log_softmax -
__global__ __launch_bounds__(64) void attn2_kernel(const unsigned char* __restrict__ H8,
                                                   const float* __restrict__ bias,
                                                   const float* __restrict__ S2,
                                                   float* __restrict__ out) {
  __shared__ __align__(16) float p_sh[64 * 4];
  __shared__ int s_sh[64];
  __shared__ float xh[4][48];
  int n = blockIdx.x, lane = threadIdx.x;
  int rs = g_rowptr[n], deg = g_rowptr[n + 1] - rs;
  float ald0 = g_ald[0 * NN + n], ald1 = g_ald[1 * NN + n];
  float ald2 = g_ald[2 * NN + n], ald3 = g_ald[3 * NN + n];
  int head = lane / 12;  // valid for lane<48
  float den0 = 0, den1 = 0, den2 = 0, den3 = 0;
  float a0 = 0, a1 = 0, a2 = 0, a3 = 0;
  for (int base = 0; base < deg; base += 64) {
    int j = base + lane;
    float p0 = 0, p1 = 0, p2 = 0, p3 = 0;
    int s = 0;
    if (j < deg) {
      s = g_esrc[rs + j];
      p0 = __expf(lrelu(g_als[0 * NN + s] + ald0)); den0 += p0;
      p1 = __expf(lrelu(g_als[1 * NN + s] + ald1)); den1 += p1;
      p2 = __expf(lrelu(g_als[2 * NN + s] + ald2)); den2 += p2;
      p3 = __expf(lrelu(g_als[3 * NN + s] + ald3)); den3 += p3;
    }
    p_sh[lane * 4 + 0] = p0; p_sh[lane * 4 + 1] = p1;
    p_sh[lane * 4 + 2] = p2; p_sh[lane * 4 + 3] = p3;
    s_sh[lane] = s;
    __syncthreads();
    int cnt = min(64, deg - base);
    if (lane < 48) {
      for (int jj = 0; jj < cnt; jj++) {
        int ss = s_sh[jj];
        float p = p_sh[jj * 4 + head];
        unsigned int hv = *(const unsigned int*)(H8 + (size_t)ss * 192 + lane * 4);
        f32x2 lo = __builtin_amdgcn_cvt_pk_f32_fp8(hv, false);
        f32x2 hi = __builtin_amdgcn_cvt_pk_f32_fp8(hv, true);
        a0 += p * lo.x;
        a1 += p * lo.y;
        a2 += p * hi.x;
        a3 += p * hi.y;
      }
    }
    __syncthreads();
  }
  den0 = wsum(den0); den1 = wsum(den1); den2 = wsum(den2); den3 = wsum(den3);
  if (lane < 48) {
    float dh = (head == 0) ? den0 : (head == 1) ? den1 : (head == 2) ? den2 : den3;
    float inv = 1.f / (dh + 1e-16f);
    int chin = (lane % 12) * 4;
    xh[head][chin + 0] = a0 * inv;
    xh[head][chin + 1] = a1 * inv;
    xh[head][chin + 2] = a2 * inv;
    xh[head][chin + 3] = a3 * inv;
  }
  __syncthreads();
  float v = 0.f;
  if (lane < NCLS)
    v = 0.25f * (xh[0][lane] + xh[1][lane] + xh[2][lane] + xh[3][lane]) + bias[lane] +
        S2[(size_t)n * NCLS + lane];
  // fused log_softmax over the 47 classes
  float mv = (lane < NCLS) ? v : -INFINITY;
#pragma unroll
  for (int o = 32; o > 0; o >>= 1) mv = fmaxf(mv, __shfl_xor(mv, o, 64));
  float ex = (lane < NCLS) ? __expf(v - mv) : 0.f;
  float s = wsum(ex);
  if (lane < NCLS) out[(size_t)n * NCLS + lane] = v - mv - logf(s);
}

// ---------------- BatchNorm over bf16 buffer (stat selected per layer) ----------------
__global__ void bn_stats_kernel(const ushortt* __restrict__ Sb, float* __restrict__ stat) {
  int c = threadIdx.x;  // 256 cols
  int rows = (NN + gridDim.x - 1) / gridDim.x;
  int r0 = blockIdx.x * rows, r1 = min(r0 + rows, NN);
  float s = 0, q = 0;
  for (int r = r0; r < r1; r++) {
    float v = bf2f(Sb[(size_t)r * 256 + c]);
    s += v;
    q += v * v;
  }
  atomicAdd(&stat[c], s);
  atomicAdd(&stat[256 + c], q);
}
// normalize + ELU -> bf16 features (SWIZZLED for the GEMM); optionally zero als/ald
__global__ void bn_norm_kernel(const ushortt* __restrict__ Sb, const float* __restrict__ gamma,
                               const float* __restrict__ beta, const float* __restrict__ stat,
                               float* __restrict__ zs, float* __restrict__ zd) {
  int i = blockIdx.x * blockDim.x + threadIdx.x;
  if (i >= NN * 256) return;
  int c = i & 255;
  int r = i >> 8;
  float mu = stat[c] * (1.f / NN);
  float var = stat[256 + c] * (1.f / NN) - mu * mu;
  float v = (bf2f(Sb[i]) - mu) * rsqrtf(var + 1e-5f) * gamma[c] + beta[c];
  v = v > 0.f ? v : (__expf(v) - 1.f);  // ELU
  g_Fb[(r << 8) | swz(r, c)] = f2bf(v);
  if (zs && i < NN * 4) {
    zs[i] = 0.f;
    zd[i] = 0.f;
  }
}

// ---------------- launch ----------------
extern "C" void kernel_launch(void* const* d_in, const int* in_sizes, int n_in,
                              void* d_out, int out_size, void* d_ws, size_t ws_size,
                              hipStream_t stream) {
  const float* x = (const float*)d_in[0];
  const int* ei = (const int*)d_in[1];
  const int* src = ei;
  const int* dst = ei + EE;
  const float* w0 = (const float*)d_in[2];
  const float* as0 = (const float*)d_in[3];
  const float* ad0 = (const float*)d_in[4];
  const float* b0 = (const float*)d_in[5];
  const float* sw0 = (const float*)d_in[6];
  const float* sb0 = (const float*)d_in[7];
  const float* gm0 = (const float*)d_in[8];
  const float* be0 = (const float*)d_in[9];
  const float* w1 = (const float*)d_in[10];
  const float* as1 = (const float*)d_in[11];
  const float* ad1 = (const float*)d_in[12];
  const float* b1 = (const float*)d_in[13];
  const float* sw1 = (const float*)d_in[14];
  const float* sb1 = (const float*)d_in[15];
  const float* gm1 = (const float*)d_in[16];
  const float* be1 = (const float*)d_in[17];
  const float* w2 = (const float*)d_in[18];
  const float* as2 = (const float*)d_in[19];
  const float* ad2 = (const float*)d_in[20];
  const float* b2 = (const float*)d_in[21];
  const float* sw2 = (const float*)d_in[22];
  const float* sb2 = (const float*)d_in[23];
  float* out = (float*)d_out;

  ushortt *Sb, *Fb, *Xb, *Wc0, *Wc1, *Wc2;
  unsigned char* H8;
  float *S2, *als, *ald, *stat;
  hipGetSymbolAddress((void**)&H8, HIP_SYMBOL(g_H8));
  hipGetSymbolAddress((void**)&Sb, HIP_SYMBOL(g_Sb));
  hipGetSymbolAddress((void**)&S2, HIP_SYMBOL(g_S2));
  hipGetSymbolAddress((void**)&Fb, HIP_SYMBOL(g_Fb));
  hipGetSymbolAddress((void**)&Xb, HIP_SYMBOL(g_Xb));
  hipGetSymbolAddress((void**)&Wc0, HIP_SYMBOL(g_Wc0));
  hipGetSymbolAddress((void**)&Wc1, HIP_SYMBOL(g_Wc1));
  hipGetSymbolAddress((void**)&Wc2, HIP_SYMBOL(g_Wc2));
  hipGetSymbolAddress((void**)&als, HIP_SYMBOL(g_als));
  hipGetSymbolAddress((void**)&ald, HIP_SYMBOL(g_ald));
  hipGetSymbolAddress((void**)&stat, HIP_SYMBOL(g_stat));

  // conversions + zero-init of counts/stat (replaces all memsets; runs first)
  conv_kernel<<<(CW0 + CW1 + CW2 + NN * 128 + NN + 1024 + 255) / 256, 256, 0, stream>>>(
      w0, sw0, w1, sw1, w2, sw2, x);

  // CSR by destination (edge_index constant across layers)
  count_kernel<<<(EE + 255) / 256, 256, 0, stream>>>(dst);
  scan1_kernel<<<SCAN_B, 256, 0, stream>>>();
  scan2_kernel<<<1, 128, 0, stream>>>();
  scan3_kernel<<<SCAN_B, 256, 0, stream>>>();
  scatter_kernel<<<(EE + 255) / 256, 256, 0, stream>>>(dst, src);

  const int gy = (NN + 63) / 64;  // 469

  // ---- layer 0 ----
  mfma_gemm<<<dim3(4, gy), 256, 0, stream>>>(Xb, Wc0, H8, Sb, nullptr, NN, 128, 512, 256,
                                             256, 256, sb0, 0, as0, ad0, als, ald);
  attn_kernel<<<NN, 64, 0, stream>>>(H8, b0, Sb);
  bn_stats_kernel<<<240, 256, 0, stream>>>(Sb, stat);
  bn_norm_kernel<<<(NN * 256 + 255) / 256, 256, 0, stream>>>(Sb, gm0, be0, stat,
                                                             nullptr, nullptr);

  // ---- layer 1 ----
  mfma_gemm<<<dim3(4, gy), 256, 0, stream>>>(Fb, Wc1, H8, Sb, nullptr, NN, 256, 512, 256,
                                             256, 256, sb1, 0, as1, ad1, als, ald);
  attn_kernel<<<NN, 64, 0, stream>>>(H8, b1, Sb);
  bn_stats_kernel<<<240, 256, 0, stream>>>(Sb, stat + 512);
  bn_norm_kernel<<<(NN * 256 + 255) / 256, 256, 0, stream>>>(Sb, gm1, be1, stat + 512,
                                                             als, ald);  // zeroes logits

  // ---- layer 2 (h fp8 padded: ld=192, 48/head; skip -> S2[N,47] fp32; logits atomic) ----
  mfma_gemm<<<dim3(2, gy), 256, 0, stream>>>(Fb, Wc2, H8, nullptr, S2, NN, 256, 235, 188,
                                             192, 47, sb2, 1, as2, ad2, als, ald);
  attn2_kernel<<<NN, 64, 0, stream>>>(H8, b2, S2, out);
}

// Round 17
// 435.924 us; speedup vs baseline: 1.0121x; 1.0121x over previous
//
#include <hip/hip_runtime.h>
#include <math.h>

#define NN 30000
#define EE 480000
#define FIN 100
#define NCLS 47
#define SCAN_B 118  // ceil(30000/256)

typedef unsigned short ushortt;
typedef __attribute__((ext_vector_type(8))) short bf16x8;
typedef __attribute__((ext_vector_type(4))) float f32x4;
typedef __attribute__((ext_vector_type(2))) float f32x2;

// ---------------- static device workspace ----------------
// Xb/Fb/Wc* use a bank-conflict-killing swizzle: within each 64-col K-window,
// 8-ushort chunk index is XORed with (row & 7) (r15: conflicts 5.85M -> 682k).
// Logits g_als/g_ald are node-major [n*4+head] (r16's head-major was neutral/worse).
__device__ unsigned char g_H8[(size_t)NN * 256];  // fp8 e4m3 h for the gathers (l2: ld=192)
__device__ ushortt g_Sb[(size_t)NN * 256];   // skip/pre-BN accumulator, bf16 (layers 0/1)
__device__ float   g_S2[(size_t)NN * 48];    // layer-2 skip, fp32 [N,47]
__device__ ushortt g_Fb[(size_t)NN * 256];   // post-BN features bf16, SWIZZLED
__device__ ushortt g_Xb[(size_t)NN * 128];   // x padded 100->128, bf16, SWIZZLED
__device__ ushortt g_Wc0[512 * 128];         // [W0 | SW0]^T bf16, SWIZZLED
__device__ ushortt g_Wc1[512 * 256];         // [W1 | SW1]^T, SWIZZLED
__device__ ushortt g_Wc2[235 * 256];         // [W2(188) | SW2(47)]^T, SWIZZLED
__device__ float g_als[NN * 4];
__device__ float g_ald[NN * 4];
__device__ int   g_rowptr[NN + 1];
__device__ int   g_counts[NN];
__device__ int   g_bsum[128];                // per-block sums for scan
__device__ int   g_esrc[EE];                 // src node in CSR (dst-sorted) order
__device__ float g_stat[1024];               // [0:512) layer0, [512:1024) layer1 sum/sumsq

// ---------------- helpers ----------------
__device__ __forceinline__ float wsum(float v) {
#pragma unroll
  for (int o = 32; o > 0; o >>= 1) v += __shfl_xor(v, o, 64);
  return v;
}
__device__ __forceinline__ float lrelu(float x) { return x > 0.f ? x : 0.2f * x; }
__device__ __forceinline__ ushortt f2bf(float f) {
  unsigned int u = __float_as_uint(f);
  unsigned int r = u + 0x7FFF + ((u >> 16) & 1);
  return (ushortt)(r >> 16);
}
__device__ __forceinline__ float bf2f(ushortt u) {
  return __uint_as_float(((unsigned int)u) << 16);
}
__device__ __forceinline__ unsigned int pk4_fp8(float f0, float f1, float f2, float f3) {
  unsigned int r = 0;
  r = __builtin_amdgcn_cvt_pk_fp8_f32(f0, f1, r, false);
  r = __builtin_amdgcn_cvt_pk_fp8_f32(f2, f3, r, true);
  return r;
}
// swizzled column index: window=64 cols, chunk=8 cols, chunk ^= (row&7)
__device__ __forceinline__ int swz(int row, int k) {
  return (k & ~63) | ((((k >> 3) & 7) ^ (row & 7)) << 3) | (k & 7);
}
// async global->LDS, 16B per lane; lds dest = base + lane*16 (wave-uniform base)
__device__ __forceinline__ void glds16(const ushortt* gp, ushortt* lp) {
  __builtin_amdgcn_global_load_lds(
      (const __attribute__((address_space(1))) unsigned int*)gp,
      (__attribute__((address_space(3))) unsigned int*)lp, 16, 0, 0);
}

// ---------------- CSR build ----------------
__global__ void count_kernel(const int* __restrict__ dst) {
  int e = blockIdx.x * blockDim.x + threadIdx.x;
  if (e < EE) atomicAdd(&g_counts[dst[e]], 1);
}
__global__ void scan1_kernel() {
  int i = blockIdx.x * 256 + threadIdx.x;
  int v = (i < NN) ? g_counts[i] : 0;
  __shared__ int sh[4];
  float fv = (float)v;
  fv = wsum(fv);
  if ((threadIdx.x & 63) == 0) sh[threadIdx.x >> 6] = (int)fv;
  __syncthreads();
  if (threadIdx.x == 0) g_bsum[blockIdx.x] = sh[0] + sh[1] + sh[2] + sh[3];
}
__global__ void scan2_kernel() {
  __shared__ int sh[128];
  int t = threadIdx.x;
  int v = (t < SCAN_B) ? g_bsum[t] : 0;
  sh[t] = v;
  __syncthreads();
  for (int off = 1; off < 128; off <<= 1) {
    int x = (t >= off) ? sh[t - off] : 0;
    __syncthreads();
    sh[t] += x;
    __syncthreads();
  }
  g_bsum[t] = sh[t] - v;  // exclusive
}
__global__ void scan3_kernel() {
  __shared__ int sh[256];
  int t = threadIdx.x;
  int i = blockIdx.x * 256 + t;
  int v = (i < NN) ? g_counts[i] : 0;
  sh[t] = v;
  __syncthreads();
  for (int off = 1; off < 256; off <<= 1) {
    int x = (t >= off) ? sh[t - off] : 0;
    __syncthreads();
    sh[t] += x;
    __syncthreads();
  }
  if (i < NN) {
    g_rowptr[i] = g_bsum[blockIdx.x] + sh[t] - v;
    g_counts[i] = 0;
  }
  if (i == NN - 1) g_rowptr[NN] = EE;
}
__global__ void scatter_kernel(const int* __restrict__ dst, const int* __restrict__ src) {
  int e = blockIdx.x * blockDim.x + threadIdx.x;
  if (e < EE) {
    int d = dst[e];
    int pos = g_rowptr[d] + atomicAdd(&g_counts[d], 1);
    g_esrc[pos] = src[e];
  }
}

// ---------------- conversions + all zero-init (runs FIRST, replaces memsets) ----------
#define CW0 (512 * 128)
#define CW1 (512 * 256)
#define CW2 (235 * 256)
__global__ void conv_kernel(const float* __restrict__ w0, const float* __restrict__ sw0,
                            const float* __restrict__ w1, const float* __restrict__ sw1,
                            const float* __restrict__ w2, const float* __restrict__ sw2,
                            const float* __restrict__ x) {
  int i = blockIdx.x * blockDim.x + threadIdx.x;
  if (i < CW0) {
    int m = i >> 7, k = i & 127;
    float v = 0.f;
    if (k < FIN) v = (m < 256) ? w0[k * 256 + m] : sw0[k * 256 + (m - 256)];
    g_Wc0[(m << 7) | swz(m, k)] = f2bf(v);
    return;
  }
  i -= CW0;
  if (i < CW1) {
    int m = i >> 8, k = i & 255;
    float v = (m < 256) ? w1[k * 256 + m] : sw1[k * 256 + (m - 256)];
    g_Wc1[(m << 8) | swz(m, k)] = f2bf(v);
    return;
  }
  i -= CW1;
  if (i < CW2) {
    int m = i >> 8, k = i & 255;
    float v = (m < 188) ? w2[(size_t)k * 188 + m] : sw2[(size_t)k * 47 + (m - 188)];
    g_Wc2[(m << 8) | swz(m, k)] = f2bf(v);
    return;
  }
  i -= CW2;
  if (i < NN * 128) {
    int r = i >> 7, k = i & 127;
    g_Xb[(r << 7) | swz(r, k)] = (k < FIN) ? f2bf(x[r * FIN + k]) : 0;
    return;
  }
  i -= NN * 128;
  if (i < NN) {
    g_counts[i] = 0;
    return;
  }
  i -= NN;
  if (i < 1024) g_stat[i] = 0.f;
}

// ---------------- MFMA GEMM, 64x128 tile, BK=64, global_load_lds, swizzled LDS ----------
// A bf16 [nrows,Kp] SWIZZLED; Wt bf16 [M][Kp] SWIZZLED; cols < S -> out8 fp8 (pad47
// remaps c -> (c/47)*48 + c%47, ld8=192); cols >= S -> skip bf16 (out2b) or fp32
// (out2f), +bias2. Attention logits fused (node-major). Single-pass epilogue: all 4
// waves dump acc into a 64x132 fp32 LDS buffer at once (2 barriers total vs 4, no
// idle-wave phases). Epilogue FULLY UNROLLED (round-7 scratch-spill lesson).
__global__ __launch_bounds__(256) void mfma_gemm(
    const ushortt* __restrict__ A, const ushortt* __restrict__ Wt,
    unsigned char* __restrict__ out8, ushortt* __restrict__ out2b,
    float* __restrict__ out2f,
    int nrows, int Kp, int M, int S, int ld8, int ld2,
    const float* __restrict__ bias2, int pad47,
    const float* __restrict__ a_s, const float* __restrict__ a_d,
    float* __restrict__ alsp, float* __restrict__ aldp) {
  // staging uses 12288 ushorts (24 KB); epilogue reuses as 64x132 fp32 (33.8 KB)
  __shared__ __align__(16) ushortt smem[16896];
  ushortt* As = smem;            // 64 x 64
  ushortt* Ws = smem + 64 * 64;  // 128 x 64
  float* Ls = (float*)smem;      // 64 x (stride 132) f32
  int t = threadIdx.x;
  int wave = t >> 6, lane = t & 63;
  int row0 = blockIdx.y * 64, col0 = blockIdx.x * 128;
  int wr = wave >> 1, wc = wave & 1;  // 2 row-halves x 2 col-halves
  int m16 = lane & 15, q = lane >> 4;
  int rin8 = lane >> 3;            // 0..7 row within 8-row staging group
  int koff = (lane & 7) * 8;       // k offset in ushorts within 64-k row

  f32x4 acc[2][4];
#pragma unroll
  for (int i = 0; i < 2; i++)
#pragma unroll
    for (int j = 0; j < 4; j++) acc[i][j] = (f32x4){0.f, 0.f, 0.f, 0.f};

  for (int k0 = 0; k0 < Kp; k0 += 64) {
#pragma unroll
    for (int r = 0; r < 2; r++) {
      int lrow = wave * 16 + r * 8;
      int ga = min(row0 + lrow + rin8, nrows - 1);
      glds16(A + (size_t)ga * Kp + k0 + koff, &As[lrow * 64]);
    }
#pragma unroll
    for (int r = 0; r < 4; r++) {
      int lrow = wave * 32 + r * 8;
      int gw = min(col0 + lrow + rin8, M - 1);
      glds16(Wt + (size_t)gw * Kp + k0 + koff, &Ws[lrow * 64]);
    }
    __syncthreads();
#pragma unroll
    for (int c = 0; c < 2; c++) {
      bf16x8 af[2], bf[4];
#pragma unroll
      for (int i = 0; i < 2; i++) {
        int row = wr * 32 + i * 16 + m16;
        int ch = (c * 4 + q) ^ (row & 7);  // de-swizzle: conflict-free across m16 rows
        af[i] = *(const bf16x8*)(&As[row * 64 + ch * 8]);
      }
#pragma unroll
      for (int i = 0; i < 4; i++) {
        int row = wc * 64 + i * 16 + m16;
        int ch = (c * 4 + q) ^ (row & 7);
        bf[i] = *(const bf16x8*)(&Ws[row * 64 + ch * 8]);
      }
#pragma unroll
      for (int rt = 0; rt < 2; rt++)
#pragma unroll
        for (int ct = 0; ct < 4; ct++)
          acc[rt][ct] = __builtin_amdgcn_mfma_f32_16x16x32_bf16(af[rt], bf[ct], acc[rt][ct], 0, 0, 0);
    }
    __syncthreads();
  }

  // ---- single-pass epilogue: all waves write disjoint acc regions, then store ----
#pragma unroll
  for (int rt = 0; rt < 2; rt++) {
#pragma unroll
    for (int ctt = 0; ctt < 4; ctt++) {
#pragma unroll
      for (int reg = 0; reg < 4; reg++) {
        int rloc = wr * 32 + rt * 16 + q * 4 + reg;  // 0..63
        Ls[rloc * 132 + wc * 64 + ctt * 16 + m16] = acc[rt][ctt][reg];
      }
    }
  }
  __syncthreads();
  bool all1 = (!pad47) && (col0 + 128 <= S);
  bool all2 = (col0 >= S);
  int row8 = t >> 3, seg = t & 7;
#pragma unroll
  for (int rr = 0; rr < 2; rr++) {
    int rloc = rr * 32 + row8;
    int grow = row0 + rloc;
    if (grow < nrows) {
      const float* lrow = Ls + rloc * 132 + seg * 16;
      int cbase = col0 + seg * 16;
      if (all1) {
        unsigned int q8[4];
#pragma unroll
        for (int kk = 0; kk < 4; kk++)
          q8[kk] = pk4_fp8(lrow[kk * 4], lrow[kk * 4 + 1], lrow[kk * 4 + 2], lrow[kk * 4 + 3]);
        uint4 v8 = {q8[0], q8[1], q8[2], q8[3]};
        *(uint4*)(out8 + (size_t)grow * ld8 + cbase) = v8;
        // fused attention-logit partials: this thread covers 16 ch of head cbase>>6
        float s_p = 0.f, d_p = 0.f;
#pragma unroll
        for (int kk = 0; kk < 16; kk++) {
          s_p += lrow[kk] * a_s[cbase + kk];
          d_p += lrow[kk] * a_d[cbase + kk];
        }
        s_p += __shfl_xor(s_p, 1, 64); s_p += __shfl_xor(s_p, 2, 64);
        d_p += __shfl_xor(d_p, 1, 64); d_p += __shfl_xor(d_p, 2, 64);
        if ((seg & 3) == 0) {
          int head = cbase >> 6;
          alsp[grow * 4 + head] = s_p;
          aldp[grow * 4 + head] = d_p;
        }
      } else if (all2) {
        const float* brow = bias2 + (cbase - S);
        // bf16 skip store (layers 0/1): 16 cols -> 8 packed uints -> 2 uint4 stores
        ushortt* orow = out2b + (size_t)grow * ld2 + (cbase - S);
        unsigned int pk[8];
#pragma unroll
        for (int kk = 0; kk < 8; kk++) {
          unsigned int lo = f2bf(lrow[kk * 2] + brow[kk * 2]);
          unsigned int hi = f2bf(lrow[kk * 2 + 1] + brow[kk * 2 + 1]);
          pk[kk] = lo | (hi << 16);
        }
        uint4 v0 = {pk[0], pk[1], pk[2], pk[3]};
        uint4 v1 = {pk[4], pk[5], pk[6], pk[7]};
        *(uint4*)(orow) = v0;
        *(uint4*)(orow + 8) = v1;
      } else {
        // layer-2 mixed tile: scalar h stores (fp8, padded 47->48) + fp32 skip cols +
        // atomic logit partials (head = c/47, at most 2 heads per thread)
        float pa0 = 0.f, pa1 = 0.f, pd0 = 0.f, pd1 = 0.f;
        int h0 = cbase / 47;
        for (int kk = 0; kk < 16; kk++) {
          int c = cbase + kk;
          if (c >= M) break;
          float v = lrow[kk];
          if (c < S) {
            int hd = c / 47, ch = c - hd * 47;
            int c1 = hd * 48 + ch;
            out8[(size_t)grow * ld8 + c1] =
                (unsigned char)(pk4_fp8(v, 0.f, 0.f, 0.f) & 0xFF);
            if (ch == 46) out8[(size_t)grow * ld8 + c1 + 1] = 0;
            float sw = a_s[hd * 47 + ch], dw = a_d[hd * 47 + ch];
            if (hd == h0) { pa0 += v * sw; pd0 += v * dw; }
            else { pa1 += v * sw; pd1 += v * dw; }
          } else {
            out2f[(size_t)grow * ld2 + (c - S)] = v + bias2[c - S];
          }
        }
        if (pad47 && cbase < S) {
          if (pa0 != 0.f || pd0 != 0.f) {
            atomicAdd(&alsp[grow * 4 + h0], pa0);
            atomicAdd(&aldp[grow * 4 + h0], pd0);
          }
          if ((pa1 != 0.f || pd1 != 0.f) && h0 + 1 < 4) {
            atomicAdd(&alsp[grow * 4 + h0 + 1], pa1);
            atomicAdd(&aldp[grow * 4 + h0 + 1], pd1);
          }
        }
      }
    }
  }
}

// ---------------- fused softmax + aggregate + skip-add, C=64 concat (fp8 gather) --------
// Skip buffer Sb is bf16 (RMW). No max-subtraction: logits are lrelu of O(1) sums;
// exp cannot overflow and softmax is shift-invariant.
__global__ __launch_bounds__(64) void attn_kernel(const unsigned char* __restrict__ H8,
                                                  const float* __restrict__ bias,
                                                  ushortt* __restrict__ Sb) {
  __shared__ __align__(16) float p_sh[64 * 4];
  __shared__ int s_sh[64];
  int n = blockIdx.x, lane = threadIdx.x;
  int rs = g_rowptr[n], deg = g_rowptr[n + 1] - rs;
  float4 ald = *(const float4*)(g_ald + n * 4);
  int q = lane >> 4;
  float den0 = 0, den1 = 0, den2 = 0, den3 = 0;
  float a0 = 0, a1 = 0, a2 = 0, a3 = 0;
  for (int base = 0; base < deg; base += 64) {
    int j = base + lane;
    float p0 = 0, p1 = 0, p2 = 0, p3 = 0;
    int s = 0;
    if (j < deg) {
      s = g_esrc[rs + j];
      float4 av = *(const float4*)(g_als + s * 4);
      p0 = __expf(lrelu(av.x + ald.x)); den0 += p0;
      p1 = __expf(lrelu(av.y + ald.y)); den1 += p1;
      p2 = __expf(lrelu(av.z + ald.z)); den2 += p2;
      p3 = __expf(lrelu(av.w + ald.w)); den3 += p3;
    }
    p_sh[lane * 4 + 0] = p0; p_sh[lane * 4 + 1] = p1;
    p_sh[lane * 4 + 2] = p2; p_sh[lane * 4 + 3] = p3;
    s_sh[lane] = s;
    __syncthreads();
    int cnt = min(64, deg - base);
    for (int jj = 0; jj < cnt; jj++) {
      int ss = s_sh[jj];
      float p = p_sh[jj * 4 + q];
      unsigned int hv = *(const unsigned int*)(H8 + (size_t)ss * 256 + 4 * lane);
      f32x2 lo = __builtin_amdgcn_cvt_pk_f32_fp8(hv, false);
      f32x2 hi = __builtin_amdgcn_cvt_pk_f32_fp8(hv, true);
      a0 += p * lo.x;
      a1 += p * lo.y;
      a2 += p * hi.x;
      a3 += p * hi.y;
    }
    __syncthreads();
  }
  den0 = wsum(den0); den1 = wsum(den1); den2 = wsum(den2); den3 = wsum(den3);
  float denq = (q == 0) ? den0 : (q == 1) ? den1 : (q == 2) ? den2 : den3;
  float inv = 1.f / (denq + 1e-16f);
  size_t o = (size_t)n * 256 + 4 * lane;
  ushort4 sv = *(const ushort4*)(Sb + o);
  float4 bv = *(const float4*)(bias + 4 * lane);
  ushort4 ov;
  ov.x = f2bf(a0 * inv + bv.x + bf2f(sv.x));
  ov.y = f2bf(a1 * inv + bv.y + bf2f(sv.y));
  ov.z = f2bf(a2 * inv + bv.z + bf2f(sv.z));
  ov.w = f2bf(a3 * inv + bv.w + bf2f(sv.w));
  *(ushort4*)(Sb + o) = ov;
}

// ---------------- layer-2: softmax + aggregate (fp8, ld=192) + mean + skip + log_softmax -
__global__ __launch_bounds__(64) void attn2_kernel(const unsigned char* __restrict__ H8,
                                                   const float* __restrict__ bias,
                                                   const float* __restrict__ S2,
                                                   float* __restrict__ out) {
  __shared__ __align__(16) float p_sh[64 * 4];
  __shared__ int s_sh[64];
  __shared__ float xh[4][48];
  int n = blockIdx.x, lane = threadIdx.x;
  int rs = g_rowptr[n], deg = g_rowptr[n + 1] - rs;
  float4 ald = *(const float4*)(g_ald + n * 4);
  int head = lane / 12;  // valid for lane<48
  float den0 = 0, den1 = 0, den2 = 0, den3 = 0;
  float a0 = 0, a1 = 0, a2 = 0, a3 = 0;
  for (int base = 0; base < deg; base += 64) {
    int j = base + lane;
    float p0 = 0, p1 = 0, p2 = 0, p3 = 0;
    int s = 0;
    if (j < deg) {
      s = g_esrc[rs + j];
      float4 av = *(const float4*)(g_als + s * 4);
      p0 = __expf(lrelu(av.x + ald.x)); den0 += p0;
      p1 = __expf(lrelu(av.y + ald.y)); den1 += p1;
      p2 = __expf(lrelu(av.z + ald.z)); den2 += p2;
      p3 = __expf(lrelu(av.w + ald.w)); den3 += p3;
    }
    p_sh[lane * 4 + 0] = p0; p_sh[lane * 4 + 1] = p1;
    p_sh[lane * 4 + 2] = p2; p_sh[lane * 4 + 3] = p3;
    s_sh[lane] = s;
    __syncthreads();
    int cnt = min(64, deg - base);
    if (lane < 48) {
      for (int jj = 0; jj < cnt; jj++) {
        int ss = s_sh[jj];
        float p = p_sh[jj * 4 + head];
        unsigned int hv = *(const unsigned int*)(H8 + (size_t)ss * 192 + lane * 4);
        f32x2 lo = __builtin_amdgcn_cvt_pk_f32_fp8(hv, false);
        f32x2 hi = __builtin_amdgcn_cvt_pk_f32_fp8(hv, true);
        a0 += p * lo.x;
        a1 += p * lo.y;
        a2 += p * hi.x;
        a3 += p * hi.y;
      }
    }
    __syncthreads();
  }
  den0 = wsum(den0); den1 = wsum(den1); den2 = wsum(den2); den3 = wsum(den3);
  if (lane < 48) {
    float dh = (head == 0) ? den0 : (head == 1) ? den1 : (head == 2) ? den2 : den3;
    float inv = 1.f / (dh + 1e-16f);
    int chin = (lane % 12) * 4;
    xh[head][chin + 0] = a0 * inv;
    xh[head][chin + 1] = a1 * inv;
    xh[head][chin + 2] = a2 * inv;
    xh[head][chin + 3] = a3 * inv;
  }
  __syncthreads();
  float v = 0.f;
  if (lane < NCLS)
    v = 0.25f * (xh[0][lane] + xh[1][lane] + xh[2][lane] + xh[3][lane]) + bias[lane] +
        S2[(size_t)n * NCLS + lane];
  // fused log_softmax over the 47 classes
  float mv = (lane < NCLS) ? v : -INFINITY;
#pragma unroll
  for (int o = 32; o > 0; o >>= 1) mv = fmaxf(mv, __shfl_xor(mv, o, 64));
  float ex = (lane < NCLS) ? __expf(v - mv) : 0.f;
  float s = wsum(ex);
  if (lane < NCLS) out[(size_t)n * NCLS + lane] = v - mv - logf(s);
}

// ---------------- BatchNorm over bf16 buffer (stat selected per layer) ----------------
__global__ void bn_stats_kernel(const ushortt* __restrict__ Sb, float* __restrict__ stat) {
  int c = threadIdx.x;  // 256 cols
  int rows = (NN + gridDim.x - 1) / gridDim.x;
  int r0 = blockIdx.x * rows, r1 = min(r0 + rows, NN);
  float s = 0, q = 0;
  for (int r = r0; r < r1; r++) {
    float v = bf2f(Sb[(size_t)r * 256 + c]);
    s += v;
    q += v * v;
  }
  atomicAdd(&stat[c], s);
  atomicAdd(&stat[256 + c], q);
}
// normalize + ELU -> bf16 features (SWIZZLED for the GEMM); optionally zero als/ald
__global__ void bn_norm_kernel(const ushortt* __restrict__ Sb, const float* __restrict__ gamma,
                               const float* __restrict__ beta, const float* __restrict__ stat,
                               float* __restrict__ zs, float* __restrict__ zd) {
  int i = blockIdx.x * blockDim.x + threadIdx.x;
  if (i >= NN * 256) return;
  int c = i & 255;
  int r = i >> 8;
  float mu = stat[c] * (1.f / NN);
  float var = stat[256 + c] * (1.f / NN) - mu * mu;
  float v = (bf2f(Sb[i]) - mu) * rsqrtf(var + 1e-5f) * gamma[c] + beta[c];
  v = v > 0.f ? v : (__expf(v) - 1.f);  // ELU
  g_Fb[(r << 8) | swz(r, c)] = f2bf(v);
  if (zs && i < NN * 4) {
    zs[i] = 0.f;
    zd[i] = 0.f;
  }
}

// ---------------- launch ----------------
extern "C" void kernel_launch(void* const* d_in, const int* in_sizes, int n_in,
                              void* d_out, int out_size, void* d_ws, size_t ws_size,
                              hipStream_t stream) {
  const float* x = (const float*)d_in[0];
  const int* ei = (const int*)d_in[1];
  const int* src = ei;
  const int* dst = ei + EE;
  const float* w0 = (const float*)d_in[2];
  const float* as0 = (const float*)d_in[3];
  const float* ad0 = (const float*)d_in[4];
  const float* b0 = (const float*)d_in[5];
  const float* sw0 = (const float*)d_in[6];
  const float* sb0 = (const float*)d_in[7];
  const float* gm0 = (const float*)d_in[8];
  const float* be0 = (const float*)d_in[9];
  const float* w1 = (const float*)d_in[10];
  const float* as1 = (const float*)d_in[11];
  const float* ad1 = (const float*)d_in[12];
  const float* b1 = (const float*)d_in[13];
  const float* sw1 = (const float*)d_in[14];
  const float* sb1 = (const float*)d_in[15];
  const float* gm1 = (const float*)d_in[16];
  const float* be1 = (const float*)d_in[17];
  const float* w2 = (const float*)d_in[18];
  const float* as2 = (const float*)d_in[19];
  const float* ad2 = (const float*)d_in[20];
  const float* b2 = (const float*)d_in[21];
  const float* sw2 = (const float*)d_in[22];
  const float* sb2 = (const float*)d_in[23];
  float* out = (float*)d_out;

  ushortt *Sb, *Fb, *Xb, *Wc0, *Wc1, *Wc2;
  unsigned char* H8;
  float *S2, *als, *ald, *stat;
  hipGetSymbolAddress((void**)&H8, HIP_SYMBOL(g_H8));
  hipGetSymbolAddress((void**)&Sb, HIP_SYMBOL(g_Sb));
  hipGetSymbolAddress((void**)&S2, HIP_SYMBOL(g_S2));
  hipGetSymbolAddress((void**)&Fb, HIP_SYMBOL(g_Fb));
  hipGetSymbolAddress((void**)&Xb, HIP_SYMBOL(g_Xb));
  hipGetSymbolAddress((void**)&Wc0, HIP_SYMBOL(g_Wc0));
  hipGetSymbolAddress((void**)&Wc1, HIP_SYMBOL(g_Wc1));
  hipGetSymbolAddress((void**)&Wc2, HIP_SYMBOL(g_Wc2));
  hipGetSymbolAddress((void**)&als, HIP_SYMBOL(g_als));
  hipGetSymbolAddress((void**)&ald, HIP_SYMBOL(g_ald));
  hipGetSymbolAddress((void**)&stat, HIP_SYMBOL(g_stat));

  // conversions + zero-init of counts/stat (replaces all memsets; runs first)
  conv_kernel<<<(CW0 + CW1 + CW2 + NN * 128 + NN + 1024 + 255) / 256, 256, 0, stream>>>(
      w0, sw0, w1, sw1, w2, sw2, x);

  // CSR by destination (edge_index constant across layers)
  count_kernel<<<(EE + 255) / 256, 256, 0, stream>>>(dst);
  scan1_kernel<<<SCAN_B, 256, 0, stream>>>();
  scan2_kernel<<<1, 128, 0, stream>>>();
  scan3_kernel<<<SCAN_B, 256, 0, stream>>>();
  scatter_kernel<<<(EE + 255) / 256, 256, 0, stream>>>(dst, src);

  const int gy = (NN + 63) / 64;  // 469

  // ---- layer 0 ----
  mfma_gemm<<<dim3(4, gy), 256, 0, stream>>>(Xb, Wc0, H8, Sb, nullptr, NN, 128, 512, 256,
                                             256, 256, sb0, 0, as0, ad0, als, ald);
  attn_kernel<<<NN, 64, 0, stream>>>(H8, b0, Sb);
  bn_stats_kernel<<<240, 256, 0, stream>>>(Sb, stat);
  bn_norm_kernel<<<(NN * 256 + 255) / 256, 256, 0, stream>>>(Sb, gm0, be0, stat,
                                                             nullptr, nullptr);

  // ---- layer 1 ----
  mfma_gemm<<<dim3(4, gy), 256, 0, stream>>>(Fb, Wc1, H8, Sb, nullptr, NN, 256, 512, 256,
                                             256, 256, sb1, 0, as1, ad1, als, ald);
  attn_kernel<<<NN, 64, 0, stream>>>(H8, b1, Sb);
  bn_stats_kernel<<<240, 256, 0, stream>>>(Sb, stat + 512);
  bn_norm_kernel<<<(NN * 256 + 255) / 256, 256, 0, stream>>>(Sb, gm1, be1, stat + 512,
                                                             als, ald);  // zeroes logits

  // ---- layer 2 (h fp8 padded: ld=192, 48/head; skip -> S2[N,47] fp32; logits atomic) ----
  mfma_gemm<<<dim3(2, gy), 256, 0, stream>>>(Fb, Wc2, H8, nullptr, S2, NN, 256, 235, 188,
                                             192, 47, sb2, 1, as2, ad2, als, ald);
  attn2_kernel<<<NN, 64, 0, stream>>>(H8, b2, S2, out);
}